// Round 6
// baseline (1098.970 us; speedup 1.0000x reference)
//
#include <hip/hip_runtime.h>
#include <float.h>

#define NV   20000
#define NP   35
#define NPTS 700000

// ws float offsets
#define S2SUM 32
#define S2SQ  96
#define S3SUM 160
#define S3SQ  288
#define MOM   864                 // sx[7] then sxx[28] (upper triangle)
#define M3MAX 1024
#define M3MIN (1024 + NV*128)

// Pure-BW pass: accumulate first+second moments of x (7 sums + 28 products).
__global__ __launch_bounds__(256) void k_moments(const float* __restrict__ x,
                                                 float* __restrict__ ws)
{
  float m[35];
  #pragma unroll
  for (int i=0;i<35;++i) m[i]=0.f;
  int stride = gridDim.x*blockDim.x;
  for (int p = blockIdx.x*blockDim.x + threadIdx.x; p < NPTS; p += stride) {
    float xv[7];
    #pragma unroll
    for (int c=0;c<7;++c) xv[c]=x[p*7+c];
    #pragma unroll
    for (int c=0;c<7;++c) m[c] += xv[c];
    int k=7;
    #pragma unroll
    for (int c=0;c<7;++c)
      #pragma unroll
      for (int d=c; d<7; ++d){ m[k]=fmaf(xv[c],xv[d],m[k]); ++k; }
  }
  #pragma unroll
  for (int i=0;i<35;++i){
    #pragma unroll
    for (int off=32;off>0;off>>=1) m[i]+=__shfl_xor(m[i],off);
  }
  __shared__ float red[4][35];
  int t=threadIdx.x, wv=t>>6, ln=t&63;
  if (ln==0){
    #pragma unroll
    for (int i=0;i<35;++i) red[wv][i]=m[i];
  }
  __syncthreads();
  if (t<35) atomicAdd(&ws[MOM+t], red[0][t]+red[1][t]+red[2][t]+red[3][t]);
}

// STAGE==2: layer1 + layer2 preact, accumulate BN2 stats. 256 thr, 4 waves.
// STAGE==3: recompute 1-2, layer3 preact, BN3 stats + per-voxel max/min. 512 thr, 8 waves.
template<int STAGE>
__global__ __launch_bounds__(STAGE==3?512:256) void k_pass(
    const float* __restrict__ x,
    const float* __restrict__ W1, const float* __restrict__ b1,
    const float* __restrict__ g1, const float* __restrict__ be1,
    const float* __restrict__ W2, const float* __restrict__ b2,
    const float* __restrict__ g2, const float* __restrict__ be2,
    const float* __restrict__ Wd, const float* __restrict__ bd,
    float* __restrict__ ws)
{
  constexpr int NW = (STAGE==3) ? 8 : 4;
  constexpr int NT = NW*64;
  __shared__ float sW1[112], sb1v[16], ssc1[16], ssh1[16];
  __shared__ float ssc2[STAGE==3?64:1], ssh2[STAGE==3?64:1];
  __shared__ __align__(16) float h1n_lds[NW][NP][16];
  __shared__ float keep_lds[NW][NP+1];
  __shared__ __align__(16) float h2n_lds[STAGE==3?NW:1][STAGE==3?NP:1][64];
  __shared__ float agg2_lds[STAGE==3?NW:1][64];
  __shared__ __align__(16) float sWd[STAGE==3?128*128:4];

  int t = threadIdx.x;
  if (t < 112) sW1[t] = W1[t];
  if (t < 16) {
    sb1v[t] = b1[t];
    // BN1 analytically from x-moments: var = w'M2w - (w'xbar)^2 (bias cancels)
    const float invN = 1.f/(float)NPTS;
    float wl[7], xb[7];
    #pragma unroll
    for (int c=0;c<7;++c){ wl[c]=W1[c*16+t]; xb[c]=ws[MOM+c]*invN; }
    float ms=0.f;
    #pragma unroll
    for (int c=0;c<7;++c) ms = fmaf(wl[c], xb[c], ms);
    const int base[7] = {0,7,13,18,22,25,27};
    float e2=0.f;
    #pragma unroll
    for (int c=0;c<7;++c)
      #pragma unroll
      for (int d=0;d<7;++d){
        int lo = c<d?c:d, hi = c<d?d:c;
        e2 = fmaf(wl[c]*wl[d], ws[MOM+7+base[lo]+(hi-lo)]*invN, e2);
      }
    float var = e2 - ms*ms;
    float sc = g1[t] * rsqrtf(var + 1e-5f);
    ssc1[t] = sc;
    ssh1[t] = fmaf(-(ms + b1[t]), sc, be1[t]);
  }
  if constexpr (STAGE==3) {
    if (t < 64) {
      const float invN = 1.f/(float)NPTS;
      float mean = ws[S2SUM+t]*invN;
      float var  = ws[S2SQ+t]*invN - mean*mean;
      float sc = g2[t]*rsqrtf(var+1e-5f);
      ssc2[t] = sc;
      ssh2[t] = fmaf(-mean, sc, be2[t]);
    }
    for (int i = t*4; i < 128*128; i += NT*4)
      *reinterpret_cast<float4*>(&sWd[i]) = *reinterpret_cast<const float4*>(&Wd[i]);
  }
  __syncthreads();

  int lane = t & 63, w = t >> 6;
  float W2r[32];
  #pragma unroll
  for (int c=0;c<32;++c) W2r[c] = W2[c*64 + lane];
  float b2r = b2[lane];
  float sc2r=0.f, sh2r=0.f, bdr0=0.f, bdr1=0.f;
  if constexpr (STAGE==3) {
    sc2r = ssc2[lane]; sh2r = ssh2[lane];
    bdr0 = bd[lane]; bdr1 = bd[64+lane];
  }
  float s2=0.f, ss2=0.f;
  float s3a=0.f, ss3a=0.f, s3b=0.f, ss3b=0.f;
  float* m3x = ws + M3MAX;
  float* m3n = ws + M3MIN;

  int wave = (blockIdx.x * NT + t) >> 6;
  int nw = (gridDim.x * NT) >> 6;
  for (int v = wave; v < NV; v += nw) {
    // ---- Phase A: lane = point ----
    int p = lane;
    float xv[7];
    float kp = 0.f;
    if (p < NP) {
      float sum = 0.f;
      #pragma unroll
      for (int c=0;c<7;++c){ xv[c] = x[(v*NP + p)*7 + c]; sum += xv[c]; }
      kp = (sum == 0.f) ? 0.f : 1.f;
    } else {
      #pragma unroll
      for (int c=0;c<7;++c) xv[c]=0.f;
    }
    float h1v[16];
    #pragma unroll
    for (int u=0;u<16;++u) h1v[u] = sb1v[u];
    #pragma unroll
    for (int c=0;c<7;++c){
      float xc = xv[c];
      #pragma unroll
      for (int u=0;u<16;++u) h1v[u] = fmaf(xc, sW1[c*16+u], h1v[u]);
    }
    float aggv[16];
    #pragma unroll
    for (int u=0;u<16;++u){
      float hn = fmaxf(0.f, fmaf(h1v[u], ssc1[u], ssh1[u]));
      h1v[u] = hn;
      aggv[u] = (p < NP) ? hn : -FLT_MAX;
    }
    #pragma unroll
    for (int u=0;u<16;++u){
      #pragma unroll
      for (int off=32; off>0; off>>=1)
        aggv[u] = fmaxf(aggv[u], __shfl_xor(aggv[u], off));
    }
    if (p < NP) {
      #pragma unroll
      for (int c=0;c<16;c+=4)
        *reinterpret_cast<float4*>(&h1n_lds[w][p][c]) =
            make_float4(h1v[c],h1v[c+1],h1v[c+2],h1v[c+3]);
      keep_lds[w][p] = kp;
    }
    // ---- Phase B: lane = channel u in [0,64) ----
    float t1 = 0.f;
    #pragma unroll
    for (int c=0;c<16;++c) t1 = fmaf(aggv[c], W2r[16+c], t1);
    float agg2u = -FLT_MAX;
    #pragma unroll
    for (int p2=0;p2<NP;++p2){
      float kpp = keep_lds[w][p2];
      float d = t1;
      #pragma unroll
      for (int c=0;c<16;c+=4){
        float4 a = *reinterpret_cast<const float4*>(&h1n_lds[w][p2][c]);
        d = fmaf(a.x, W2r[c],   d);
        d = fmaf(a.y, W2r[c+1], d);
        d = fmaf(a.z, W2r[c+2], d);
        d = fmaf(a.w, W2r[c+3], d);
      }
      float h2p = fmaf(kpp, d, b2r);
      if constexpr (STAGE==2) {
        s2 += h2p; ss2 = fmaf(h2p, h2p, ss2);
      } else {
        float h2nv = fmaxf(0.f, fmaf(h2p, sc2r, sh2r));
        agg2u = fmaxf(agg2u, h2nv);
        h2n_lds[w][p2][lane] = h2nv;
      }
    }
    // ---- Phase C (stage 3): lane owns output channels {lane, lane+64} ----
    if constexpr (STAGE==3) {
      agg2_lds[w][lane] = agg2u;
      float t3a=0.f, t3b=0.f;
      #pragma unroll
      for (int c=0;c<64;++c){
        float a = agg2_lds[w][c];
        t3a = fmaf(a, sWd[(64+c)*128 + lane],      t3a);
        t3b = fmaf(a, sWd[(64+c)*128 + 64 + lane], t3b);
      }
      float acc0[NP], acc1[NP];
      #pragma unroll
      for (int p2=0;p2<NP;++p2){ acc0[p2]=0.f; acc1[p2]=0.f; }
      for (int cb=0; cb<64; cb+=4){
        float w00=sWd[(cb+0)*128+lane],    w01=sWd[(cb+1)*128+lane],
              w02=sWd[(cb+2)*128+lane],    w03=sWd[(cb+3)*128+lane];
        float w10=sWd[(cb+0)*128+64+lane], w11=sWd[(cb+1)*128+64+lane],
              w12=sWd[(cb+2)*128+64+lane], w13=sWd[(cb+3)*128+64+lane];
        #pragma unroll
        for (int p2=0;p2<NP;++p2){
          float4 a = *reinterpret_cast<const float4*>(&h2n_lds[w][p2][cb]);
          acc0[p2] = fmaf(a.x,w00, fmaf(a.y,w01, fmaf(a.z,w02, fmaf(a.w,w03, acc0[p2]))));
          acc1[p2] = fmaf(a.x,w10, fmaf(a.y,w11, fmaf(a.z,w12, fmaf(a.w,w13, acc1[p2]))));
        }
      }
      float mx0=-FLT_MAX, mx1=-FLT_MAX, mn0=FLT_MAX, mn1=FLT_MAX;
      #pragma unroll
      for (int p2=0;p2<NP;++p2){
        float kpp = keep_lds[w][p2];
        float h0 = fmaf(kpp, acc0[p2]+t3a, bdr0);
        float h1 = fmaf(kpp, acc1[p2]+t3b, bdr1);
        s3a += h0; ss3a = fmaf(h0,h0,ss3a);
        s3b += h1; ss3b = fmaf(h1,h1,ss3b);
        mx0=fmaxf(mx0,h0); mn0=fminf(mn0,h0);
        mx1=fmaxf(mx1,h1); mn1=fminf(mn1,h1);
      }
      m3x[v*128+lane]    = mx0;  m3x[v*128+64+lane] = mx1;
      m3n[v*128+lane]    = mn0;  m3n[v*128+64+lane] = mn1;
    }
  }
  if constexpr (STAGE==2) {
    atomicAdd(&ws[S2SUM+lane], s2);
    atomicAdd(&ws[S2SQ +lane], ss2);
  } else {
    atomicAdd(&ws[S3SUM+lane],    s3a);
    atomicAdd(&ws[S3SUM+64+lane], s3b);
    atomicAdd(&ws[S3SQ+lane],     ss3a);
    atomicAdd(&ws[S3SQ+64+lane],  ss3b);
  }
}

__global__ __launch_bounds__(256) void k_scatter(const float* __restrict__ ws,
    const int* __restrict__ coord, const float* __restrict__ gd,
    const float* __restrict__ bed, float* __restrict__ out)
{
  __shared__ float s3c[128], s3h[128];
  int t = threadIdx.x;
  if (t < 128) {
    const float invN = 1.f/(float)NPTS;
    float mean = ws[S3SUM+t]*invN;
    float var  = ws[S3SQ+t]*invN - mean*mean;
    float sc = gd[t]*rsqrtf(var+1e-5f);
    s3c[t]=sc; s3h[t]=fmaf(-mean,sc,bed[t]);
  }
  __syncthreads();
  int tid = blockIdx.x*256 + t;
  if (tid >= NV*128) return;
  int v = tid >> 7, u = tid & 127;
  float sc = s3c[u], sh = s3h[u];
  // BN is monotone per channel: pick max or min of pre-BN h3 by sign of scale.
  float m = (sc >= 0.f) ? ws[M3MAX+tid] : ws[M3MIN+tid];
  float val = fmaxf(0.f, fmaf(m, sc, sh));
  if (val != 0.f) {
    int z = coord[v*3+0], y = coord[v*3+1], xx = coord[v*3+2];
    atomicAdd(&out[((u*10+z)*200+y)*176+xx], val);
  }
}

extern "C" void kernel_launch(void* const* d_in, const int* in_sizes, int n_in,
                              void* d_out, int out_size, void* d_ws, size_t ws_size,
                              hipStream_t stream)
{
  const float* x   = (const float*)d_in[0];
  const int*   coord = (const int*)d_in[1];
  const float* W1  = (const float*)d_in[2];
  const float* b1  = (const float*)d_in[3];
  const float* g1  = (const float*)d_in[4];
  const float* be1 = (const float*)d_in[5];
  const float* W2  = (const float*)d_in[6];
  const float* b2  = (const float*)d_in[7];
  const float* g2  = (const float*)d_in[8];
  const float* be2 = (const float*)d_in[9];
  const float* Wd  = (const float*)d_in[10];
  const float* bd  = (const float*)d_in[11];
  const float* gd  = (const float*)d_in[12];
  const float* bed = (const float*)d_in[13];
  float* out = (float*)d_out;
  float* ws  = (float*)d_ws;

  hipMemsetAsync(ws, 0, 1024*sizeof(float), stream);
  hipMemsetAsync(out, 0, (size_t)out_size*sizeof(float), stream);

  k_moments<<<640,256,0,stream>>>(x, ws);
  k_pass<2><<<1024,256,0,stream>>>(x, W1,b1,g1,be1, W2,b2,g2,be2, Wd,bd, ws);
  k_pass<3><<<256,512,0,stream>>>(x, W1,b1,g1,be1, W2,b2,g2,be2, Wd,bd, ws);
  k_scatter<<<10000,256,0,stream>>>(ws, coord, gd, bed, out);
}

// Round 7
// 1058.798 us; speedup vs baseline: 1.0379x; 1.0379x over previous
//
#include <hip/hip_runtime.h>
#include <float.h>

#define NV   20000
#define NP   35
#define NPTS 700000

// ws float offsets
#define S2SUM 32
#define S2SQ  96
#define S3SUM 160
#define S3SQ  288
#define MOM   864                 // sx[7] then sxx[28] (upper triangle)
#define M3MAX 1024
#define M3MIN (1024 + NV*128)

// Pure-BW pass: accumulate first+second moments of x (7 sums + 28 products).
__global__ __launch_bounds__(256) void k_moments(const float* __restrict__ x,
                                                 float* __restrict__ ws)
{
  float m[35];
  #pragma unroll
  for (int i=0;i<35;++i) m[i]=0.f;
  int stride = gridDim.x*blockDim.x;
  for (int p = blockIdx.x*blockDim.x + threadIdx.x; p < NPTS; p += stride) {
    float xv[7];
    #pragma unroll
    for (int c=0;c<7;++c) xv[c]=x[p*7+c];
    #pragma unroll
    for (int c=0;c<7;++c) m[c] += xv[c];
    int k=7;
    #pragma unroll
    for (int c=0;c<7;++c)
      #pragma unroll
      for (int d=c; d<7; ++d){ m[k]=fmaf(xv[c],xv[d],m[k]); ++k; }
  }
  #pragma unroll
  for (int i=0;i<35;++i){
    #pragma unroll
    for (int off=32;off>0;off>>=1) m[i]+=__shfl_xor(m[i],off);
  }
  __shared__ float red[4][35];
  int t=threadIdx.x, wv=t>>6, ln=t&63;
  if (ln==0){
    #pragma unroll
    for (int i=0;i<35;++i) red[wv][i]=m[i];
  }
  __syncthreads();
  if (t<35) atomicAdd(&ws[MOM+t], red[0][t]+red[1][t]+red[2][t]+red[3][t]);
}

// STAGE==2: layer1 + layer2 preact, accumulate BN2 stats. 256 thr (4 waves), VGPR<=128.
// STAGE==3: recompute 1-2, layer3 preact, BN3 stats + per-voxel max/min.
//           512 thr (8 waves), launch_bounds(512,2) -> VGPR<=256, no spill (acc0/acc1).
template<int STAGE>
__global__ __launch_bounds__(STAGE==3?512:256, STAGE==3?2:4) void k_pass(
    const float* __restrict__ x,
    const float* __restrict__ W1, const float* __restrict__ b1,
    const float* __restrict__ g1, const float* __restrict__ be1,
    const float* __restrict__ W2, const float* __restrict__ b2,
    const float* __restrict__ g2, const float* __restrict__ be2,
    const float* __restrict__ Wd, const float* __restrict__ bd,
    float* __restrict__ ws)
{
  constexpr int NW = (STAGE==3) ? 8 : 4;
  constexpr int NT = NW*64;
  __shared__ float sW1[112], sb1v[16], ssc1[16], ssh1[16];
  __shared__ float ssc2[STAGE==3?64:1], ssh2[STAGE==3?64:1];
  // 20-float rows (80B stride): measured 0 bank conflicts (round 2). Slot 16 = keep.
  __shared__ __align__(16) float h1n_lds[NW][NP][20];
  __shared__ __align__(16) float h2n_lds[STAGE==3?NW:1][STAGE==3?NP:1][64];
  __shared__ float agg2_lds[STAGE==3?NW:1][64];
  __shared__ __align__(16) float sWd[STAGE==3?128*128:4];

  int t = threadIdx.x;
  if (t < 112) sW1[t] = W1[t];
  if (t < 16) {
    sb1v[t] = b1[t];
    // BN1 analytically from x-moments: var = w'M2w - (w'xbar)^2 (bias cancels)
    const float invN = 1.f/(float)NPTS;
    float wl[7], xb[7];
    #pragma unroll
    for (int c=0;c<7;++c){ wl[c]=W1[c*16+t]; xb[c]=ws[MOM+c]*invN; }
    float ms=0.f;
    #pragma unroll
    for (int c=0;c<7;++c) ms = fmaf(wl[c], xb[c], ms);
    const int base[7] = {0,7,13,18,22,25,27};
    float e2=0.f;
    #pragma unroll
    for (int c=0;c<7;++c)
      #pragma unroll
      for (int d=0;d<7;++d){
        int lo = c<d?c:d, hi = c<d?d:c;
        e2 = fmaf(wl[c]*wl[d], ws[MOM+7+base[lo]+(hi-lo)]*invN, e2);
      }
    float var = e2 - ms*ms;
    float sc = g1[t] * rsqrtf(var + 1e-5f);
    ssc1[t] = sc;
    ssh1[t] = fmaf(-(ms + b1[t]), sc, be1[t]);
  }
  if constexpr (STAGE==3) {
    if (t < 64) {
      const float invN = 1.f/(float)NPTS;
      float mean = ws[S2SUM+t]*invN;
      float var  = ws[S2SQ+t]*invN - mean*mean;
      float sc = g2[t]*rsqrtf(var+1e-5f);
      ssc2[t] = sc;
      ssh2[t] = fmaf(-mean, sc, be2[t]);
    }
    for (int i = t*4; i < 128*128; i += NT*4)
      *reinterpret_cast<float4*>(&sWd[i]) = *reinterpret_cast<const float4*>(&Wd[i]);
  }
  __syncthreads();

  int lane = t & 63, w = t >> 6;
  float W2r[32];
  #pragma unroll
  for (int c=0;c<32;++c) W2r[c] = W2[c*64 + lane];
  float b2r = b2[lane];
  float sc2r=0.f, sh2r=0.f, bdr0=0.f, bdr1=0.f;
  if constexpr (STAGE==3) {
    sc2r = ssc2[lane]; sh2r = ssh2[lane];
    bdr0 = bd[lane]; bdr1 = bd[64+lane];
  }
  float s2=0.f, ss2=0.f;
  float s3a=0.f, ss3a=0.f, s3b=0.f, ss3b=0.f;
  float* m3x = ws + M3MAX;
  float* m3n = ws + M3MIN;

  int wave = (blockIdx.x * NT + t) >> 6;
  int nw = (gridDim.x * NT) >> 6;
  for (int v = wave; v < NV; v += nw) {
    // ---- Phase A: lane = point ----
    int p = lane;
    float xv[7];
    float kp = 0.f;
    if (p < NP) {
      float sum = 0.f;
      #pragma unroll
      for (int c=0;c<7;++c){ xv[c] = x[(v*NP + p)*7 + c]; sum += xv[c]; }
      kp = (sum == 0.f) ? 0.f : 1.f;
    } else {
      #pragma unroll
      for (int c=0;c<7;++c) xv[c]=0.f;
    }
    float h1v[16];
    #pragma unroll
    for (int u=0;u<16;++u) h1v[u] = sb1v[u];
    #pragma unroll
    for (int c=0;c<7;++c){
      float xc = xv[c];
      #pragma unroll
      for (int u=0;u<16;++u) h1v[u] = fmaf(xc, sW1[c*16+u], h1v[u]);
    }
    float aggv[16];
    #pragma unroll
    for (int u=0;u<16;++u){
      float hn = fmaxf(0.f, fmaf(h1v[u], ssc1[u], ssh1[u]));
      h1v[u] = hn;
      aggv[u] = (p < NP) ? hn : -FLT_MAX;
    }
    #pragma unroll
    for (int u=0;u<16;++u){
      #pragma unroll
      for (int off=32; off>0; off>>=1)
        aggv[u] = fmaxf(aggv[u], __shfl_xor(aggv[u], off));
    }
    if (p < NP) {
      #pragma unroll
      for (int c=0;c<16;c+=4)
        *reinterpret_cast<float4*>(&h1n_lds[w][p][c]) =
            make_float4(h1v[c],h1v[c+1],h1v[c+2],h1v[c+3]);
      h1n_lds[w][p][16] = kp;
    }
    // ---- Phase B: lane = channel u in [0,64) ----
    float t1 = 0.f;
    #pragma unroll
    for (int c=0;c<16;++c) t1 = fmaf(aggv[c], W2r[16+c], t1);
    float agg2u = -FLT_MAX;
    #pragma unroll
    for (int p2=0;p2<NP;++p2){
      float kpp = h1n_lds[w][p2][16];
      float d = t1;
      #pragma unroll
      for (int c=0;c<16;c+=4){
        float4 a = *reinterpret_cast<const float4*>(&h1n_lds[w][p2][c]);
        d = fmaf(a.x, W2r[c],   d);
        d = fmaf(a.y, W2r[c+1], d);
        d = fmaf(a.z, W2r[c+2], d);
        d = fmaf(a.w, W2r[c+3], d);
      }
      float h2p = fmaf(kpp, d, b2r);
      if constexpr (STAGE==2) {
        s2 += h2p; ss2 = fmaf(h2p, h2p, ss2);
      } else {
        float h2nv = fmaxf(0.f, fmaf(h2p, sc2r, sh2r));
        agg2u = fmaxf(agg2u, h2nv);
        h2n_lds[w][p2][lane] = h2nv;
      }
    }
    // ---- Phase C (stage 3): lane owns output channels {lane, lane+64} ----
    if constexpr (STAGE==3) {
      agg2_lds[w][lane] = agg2u;
      float t3a=0.f, t3b=0.f;
      #pragma unroll
      for (int c=0;c<64;++c){
        float a = agg2_lds[w][c];
        t3a = fmaf(a, sWd[(64+c)*128 + lane],      t3a);
        t3b = fmaf(a, sWd[(64+c)*128 + 64 + lane], t3b);
      }
      float acc0[NP], acc1[NP];
      #pragma unroll
      for (int p2=0;p2<NP;++p2){ acc0[p2]=0.f; acc1[p2]=0.f; }
      for (int cb=0; cb<64; cb+=4){
        float w00=sWd[(cb+0)*128+lane],    w01=sWd[(cb+1)*128+lane],
              w02=sWd[(cb+2)*128+lane],    w03=sWd[(cb+3)*128+lane];
        float w10=sWd[(cb+0)*128+64+lane], w11=sWd[(cb+1)*128+64+lane],
              w12=sWd[(cb+2)*128+64+lane], w13=sWd[(cb+3)*128+64+lane];
        #pragma unroll
        for (int p2=0;p2<NP;++p2){
          float4 a = *reinterpret_cast<const float4*>(&h2n_lds[w][p2][cb]);
          acc0[p2] = fmaf(a.x,w00, fmaf(a.y,w01, fmaf(a.z,w02, fmaf(a.w,w03, acc0[p2]))));
          acc1[p2] = fmaf(a.x,w10, fmaf(a.y,w11, fmaf(a.z,w12, fmaf(a.w,w13, acc1[p2]))));
        }
      }
      float mx0=-FLT_MAX, mx1=-FLT_MAX, mn0=FLT_MAX, mn1=FLT_MAX;
      #pragma unroll
      for (int p2=0;p2<NP;++p2){
        float kpp = h1n_lds[w][p2][16];
        float h0 = fmaf(kpp, acc0[p2]+t3a, bdr0);
        float h1 = fmaf(kpp, acc1[p2]+t3b, bdr1);
        s3a += h0; ss3a = fmaf(h0,h0,ss3a);
        s3b += h1; ss3b = fmaf(h1,h1,ss3b);
        mx0=fmaxf(mx0,h0); mn0=fminf(mn0,h0);
        mx1=fmaxf(mx1,h1); mn1=fminf(mn1,h1);
      }
      m3x[v*128+lane]    = mx0;  m3x[v*128+64+lane] = mx1;
      m3n[v*128+lane]    = mn0;  m3n[v*128+64+lane] = mn1;
    }
  }
  if constexpr (STAGE==2) {
    atomicAdd(&ws[S2SUM+lane], s2);
    atomicAdd(&ws[S2SQ +lane], ss2);
  } else {
    atomicAdd(&ws[S3SUM+lane],    s3a);
    atomicAdd(&ws[S3SUM+64+lane], s3b);
    atomicAdd(&ws[S3SQ+lane],     ss3a);
    atomicAdd(&ws[S3SQ+64+lane],  ss3b);
  }
}

__global__ __launch_bounds__(256) void k_scatter(const float* __restrict__ ws,
    const int* __restrict__ coord, const float* __restrict__ gd,
    const float* __restrict__ bed, float* __restrict__ out)
{
  __shared__ float s3c[128], s3h[128];
  int t = threadIdx.x;
  if (t < 128) {
    const float invN = 1.f/(float)NPTS;
    float mean = ws[S3SUM+t]*invN;
    float var  = ws[S3SQ+t]*invN - mean*mean;
    float sc = gd[t]*rsqrtf(var+1e-5f);
    s3c[t]=sc; s3h[t]=fmaf(-mean,sc,bed[t]);
  }
  __syncthreads();
  int tid = blockIdx.x*256 + t;
  if (tid >= NV*128) return;
  int v = tid >> 7, u = tid & 127;
  float sc = s3c[u], sh = s3h[u];
  // BN is monotone per channel: pick max or min of pre-BN h3 by sign of scale.
  float m = (sc >= 0.f) ? ws[M3MAX+tid] : ws[M3MIN+tid];
  float val = fmaxf(0.f, fmaf(m, sc, sh));
  if (val != 0.f) {
    int z = coord[v*3+0], y = coord[v*3+1], xx = coord[v*3+2];
    atomicAdd(&out[((u*10+z)*200+y)*176+xx], val);
  }
}

extern "C" void kernel_launch(void* const* d_in, const int* in_sizes, int n_in,
                              void* d_out, int out_size, void* d_ws, size_t ws_size,
                              hipStream_t stream)
{
  const float* x   = (const float*)d_in[0];
  const int*   coord = (const int*)d_in[1];
  const float* W1  = (const float*)d_in[2];
  const float* b1  = (const float*)d_in[3];
  const float* g1  = (const float*)d_in[4];
  const float* be1 = (const float*)d_in[5];
  const float* W2  = (const float*)d_in[6];
  const float* b2  = (const float*)d_in[7];
  const float* g2  = (const float*)d_in[8];
  const float* be2 = (const float*)d_in[9];
  const float* Wd  = (const float*)d_in[10];
  const float* bd  = (const float*)d_in[11];
  const float* gd  = (const float*)d_in[12];
  const float* bed = (const float*)d_in[13];
  float* out = (float*)d_out;
  float* ws  = (float*)d_ws;

  hipMemsetAsync(ws, 0, 1024*sizeof(float), stream);
  hipMemsetAsync(out, 0, (size_t)out_size*sizeof(float), stream);

  k_moments<<<640,256,0,stream>>>(x, ws);
  k_pass<2><<<1024,256,0,stream>>>(x, W1,b1,g1,be1, W2,b2,g2,be2, Wd,bd, ws);
  k_pass<3><<<256,512,0,stream>>>(x, W1,b1,g1,be1, W2,b2,g2,be2, Wd,bd, ws);
  k_scatter<<<10000,256,0,stream>>>(ws, coord, gd, bed, out);
}

// Round 10
// 1053.068 us; speedup vs baseline: 1.0436x; 1.0054x over previous
//
#include <hip/hip_runtime.h>
#include <float.h>

#define NV   20000
#define NP   35
#define NPTS 700000

// ws float offsets
#define S2SUM 32
#define S2SQ  96
#define S3SUM 160
#define S3SQ  288
#define MOM   864                 // sx[7] then sxx[28] (upper triangle)
#define M3MAX 1024
#define M3MIN (1024 + NV*128)

// Pure-BW pass: accumulate first+second moments of x (7 sums + 28 products).
__global__ __launch_bounds__(256) void k_moments(const float* __restrict__ x,
                                                 float* __restrict__ ws)
{
  float m[35];
  #pragma unroll
  for (int i=0;i<35;++i) m[i]=0.f;
  int stride = gridDim.x*blockDim.x;
  for (int p = blockIdx.x*blockDim.x + threadIdx.x; p < NPTS; p += stride) {
    float xv[7];
    #pragma unroll
    for (int c=0;c<7;++c) xv[c]=x[p*7+c];
    #pragma unroll
    for (int c=0;c<7;++c) m[c] += xv[c];
    int k=7;
    #pragma unroll
    for (int c=0;c<7;++c)
      #pragma unroll
      for (int d=c; d<7; ++d){ m[k]=fmaf(xv[c],xv[d],m[k]); ++k; }
  }
  #pragma unroll
  for (int i=0;i<35;++i){
    #pragma unroll
    for (int off=32;off>0;off>>=1) m[i]+=__shfl_xor(m[i],off);
  }
  __shared__ float red[4][35];
  int t=threadIdx.x, wv=t>>6, ln=t&63;
  if (ln==0){
    #pragma unroll
    for (int i=0;i<35;++i) red[wv][i]=m[i];
  }
  __syncthreads();
  if (t<35) atomicAdd(&ws[MOM+t], red[0][t]+red[1][t]+red[2][t]+red[3][t]);
}

// Shared BN1-from-moments epilogue (thread t<16 computes scale/shift for ch t).
__device__ __forceinline__ void bn1_setup(int t, const float* __restrict__ W1,
    const float* __restrict__ b1, const float* __restrict__ g1,
    const float* __restrict__ be1, const float* __restrict__ ws,
    float* ssc1, float* ssh1, float* sb1v)
{
  if (t < 16) {
    sb1v[t] = b1[t];
    const float invN = 1.f/(float)NPTS;
    float wl[7], xb[7];
    #pragma unroll
    for (int c=0;c<7;++c){ wl[c]=W1[c*16+t]; xb[c]=ws[MOM+c]*invN; }
    float ms=0.f;
    #pragma unroll
    for (int c=0;c<7;++c) ms = fmaf(wl[c], xb[c], ms);
    const int base[7] = {0,7,13,18,22,25,27};
    float e2=0.f;
    #pragma unroll
    for (int c=0;c<7;++c)
      #pragma unroll
      for (int d=0;d<7;++d){
        int lo = c<d?c:d, hi = c<d?d:c;
        e2 = fmaf(wl[c]*wl[d], ws[MOM+7+base[lo]+(hi-lo)]*invN, e2);
      }
    float var = e2 - ms*ms;
    float sc = g1[t] * rsqrtf(var + 1e-5f);
    ssc1[t] = sc;
    ssh1[t] = fmaf(-(ms + b1[t]), sc, be1[t]);
  }
}

// layer1 + layer2 preact, accumulate BN2 stats. 256 thr (4 waves).
__global__ __launch_bounds__(256, 4) void k_pass2(
    const float* __restrict__ x,
    const float* __restrict__ W1, const float* __restrict__ b1,
    const float* __restrict__ g1, const float* __restrict__ be1,
    const float* __restrict__ W2, const float* __restrict__ b2,
    float* __restrict__ ws)
{
  constexpr int NW = 4, NT = 256;
  __shared__ float sW1[112], sb1v[16], ssc1[16], ssh1[16];
  __shared__ __align__(16) float h1n_lds[NW][NP][20];  // slot 16 = keep

  int t = threadIdx.x;
  if (t < 112) sW1[t] = W1[t];
  bn1_setup(t, W1, b1, g1, be1, ws, ssc1, ssh1, sb1v);
  __syncthreads();

  int lane = t & 63, w = t >> 6;
  float W2r[32];
  #pragma unroll
  for (int c=0;c<32;++c) W2r[c] = W2[c*64 + lane];
  float b2r = b2[lane];
  float s2=0.f, ss2=0.f;

  int wave = (blockIdx.x * NT + t) >> 6;
  int nw = (gridDim.x * NT) >> 6;
  for (int v = wave; v < NV; v += nw) {
    // ---- Phase A: lane = point ----
    int p = lane;
    float xv[7];
    float kp = 0.f;
    if (p < NP) {
      float sum = 0.f;
      #pragma unroll
      for (int c=0;c<7;++c){ xv[c] = x[(v*NP + p)*7 + c]; sum += xv[c]; }
      kp = (sum == 0.f) ? 0.f : 1.f;
    } else {
      #pragma unroll
      for (int c=0;c<7;++c) xv[c]=0.f;
    }
    float h1v[16];
    #pragma unroll
    for (int u=0;u<16;++u) h1v[u] = sb1v[u];
    #pragma unroll
    for (int c=0;c<7;++c){
      float xc = xv[c];
      #pragma unroll
      for (int u=0;u<16;++u) h1v[u] = fmaf(xc, sW1[c*16+u], h1v[u]);
    }
    float aggv[16];
    #pragma unroll
    for (int u=0;u<16;++u){
      float hn = fmaxf(0.f, fmaf(h1v[u], ssc1[u], ssh1[u]));
      h1v[u] = hn;
      aggv[u] = (p < NP) ? hn : -FLT_MAX;
    }
    #pragma unroll
    for (int u=0;u<16;++u){
      #pragma unroll
      for (int off=32; off>0; off>>=1)
        aggv[u] = fmaxf(aggv[u], __shfl_xor(aggv[u], off));
    }
    if (p < NP) {
      #pragma unroll
      for (int c=0;c<16;c+=4)
        *reinterpret_cast<float4*>(&h1n_lds[w][p][c]) =
            make_float4(h1v[c],h1v[c+1],h1v[c+2],h1v[c+3]);
      h1n_lds[w][p][16] = kp;
    }
    // ---- Phase B: lane = channel u in [0,64) ----
    float t1 = 0.f;
    #pragma unroll
    for (int c=0;c<16;++c) t1 = fmaf(aggv[c], W2r[16+c], t1);
    #pragma unroll
    for (int p2=0;p2<NP;++p2){
      float kpp = h1n_lds[w][p2][16];
      float d = t1;
      #pragma unroll
      for (int c=0;c<16;c+=4){
        float4 a = *reinterpret_cast<const float4*>(&h1n_lds[w][p2][c]);
        d = fmaf(a.x, W2r[c],   d);
        d = fmaf(a.y, W2r[c+1], d);
        d = fmaf(a.z, W2r[c+2], d);
        d = fmaf(a.w, W2r[c+3], d);
      }
      float h2p = fmaf(kpp, d, b2r);
      s2 += h2p; ss2 = fmaf(h2p, h2p, ss2);
    }
  }
  atomicAdd(&ws[S2SUM+lane], s2);
  atomicAdd(&ws[S2SQ +lane], ss2);
}

// recompute 1-2, layer3 preact, BN3 stats + per-voxel max/min.
// 512 thr (8 waves). amdgpu_waves_per_eu(2,2): pin allocator to 2 waves/EU ->
// VGPR budget 256 (round-2 proved ~200 regs spill-free; launch_bounds(512,2)
// gave 128 -> 1.3 GB scratch traffic).
__global__ __attribute__((amdgpu_waves_per_eu(2, 2)))
__launch_bounds__(512) void k_pass3(
    const float* __restrict__ x,
    const float* __restrict__ W1, const float* __restrict__ b1,
    const float* __restrict__ g1, const float* __restrict__ be1,
    const float* __restrict__ W2, const float* __restrict__ b2,
    const float* __restrict__ g2, const float* __restrict__ be2,
    const float* __restrict__ Wd, const float* __restrict__ bd,
    float* __restrict__ ws)
{
  constexpr int NW = 8, NT = 512;
  __shared__ float sW1[112], sb1v[16], ssc1[16], ssh1[16];
  __shared__ float ssc2[64], ssh2[64];
  __shared__ __align__(16) float h1n_lds[NW][NP][20];  // slot 16 = keep
  __shared__ __align__(16) float h2n_lds[NW][NP][64];
  __shared__ float agg2_lds[NW][64];
  __shared__ __align__(16) float sWd[128*128];

  int t = threadIdx.x;
  if (t < 112) sW1[t] = W1[t];
  bn1_setup(t, W1, b1, g1, be1, ws, ssc1, ssh1, sb1v);
  if (t < 64) {
    const float invN = 1.f/(float)NPTS;
    float mean = ws[S2SUM+t]*invN;
    float var  = ws[S2SQ+t]*invN - mean*mean;
    float sc = g2[t]*rsqrtf(var+1e-5f);
    ssc2[t] = sc;
    ssh2[t] = fmaf(-mean, sc, be2[t]);
  }
  for (int i = t*4; i < 128*128; i += NT*4)
    *reinterpret_cast<float4*>(&sWd[i]) = *reinterpret_cast<const float4*>(&Wd[i]);
  __syncthreads();

  int lane = t & 63, w = t >> 6;
  float W2r[32];
  #pragma unroll
  for (int c=0;c<32;++c) W2r[c] = W2[c*64 + lane];
  float b2r = b2[lane];
  float sc2r = ssc2[lane], sh2r = ssh2[lane];
  float bdr0 = bd[lane], bdr1 = bd[64+lane];
  float s3a=0.f, ss3a=0.f, s3b=0.f, ss3b=0.f;
  float* m3x = ws + M3MAX;
  float* m3n = ws + M3MIN;

  int wave = (blockIdx.x * NT + t) >> 6;
  int nw = (gridDim.x * NT) >> 6;
  for (int v = wave; v < NV; v += nw) {
    // ---- Phase A: lane = point ----
    int p = lane;
    float xv[7];
    float kp = 0.f;
    if (p < NP) {
      float sum = 0.f;
      #pragma unroll
      for (int c=0;c<7;++c){ xv[c] = x[(v*NP + p)*7 + c]; sum += xv[c]; }
      kp = (sum == 0.f) ? 0.f : 1.f;
    } else {
      #pragma unroll
      for (int c=0;c<7;++c) xv[c]=0.f;
    }
    float h1v[16];
    #pragma unroll
    for (int u=0;u<16;++u) h1v[u] = sb1v[u];
    #pragma unroll
    for (int c=0;c<7;++c){
      float xc = xv[c];
      #pragma unroll
      for (int u=0;u<16;++u) h1v[u] = fmaf(xc, sW1[c*16+u], h1v[u]);
    }
    float aggv[16];
    #pragma unroll
    for (int u=0;u<16;++u){
      float hn = fmaxf(0.f, fmaf(h1v[u], ssc1[u], ssh1[u]));
      h1v[u] = hn;
      aggv[u] = (p < NP) ? hn : -FLT_MAX;
    }
    #pragma unroll
    for (int u=0;u<16;++u){
      #pragma unroll
      for (int off=32; off>0; off>>=1)
        aggv[u] = fmaxf(aggv[u], __shfl_xor(aggv[u], off));
    }
    if (p < NP) {
      #pragma unroll
      for (int c=0;c<16;c+=4)
        *reinterpret_cast<float4*>(&h1n_lds[w][p][c]) =
            make_float4(h1v[c],h1v[c+1],h1v[c+2],h1v[c+3]);
      h1n_lds[w][p][16] = kp;
    }
    // ---- Phase B: lane = channel u in [0,64) ----
    float t1 = 0.f;
    #pragma unroll
    for (int c=0;c<16;++c) t1 = fmaf(aggv[c], W2r[16+c], t1);
    float agg2u = -FLT_MAX;
    #pragma unroll
    for (int p2=0;p2<NP;++p2){
      float kpp = h1n_lds[w][p2][16];
      float d = t1;
      #pragma unroll
      for (int c=0;c<16;c+=4){
        float4 a = *reinterpret_cast<const float4*>(&h1n_lds[w][p2][c]);
        d = fmaf(a.x, W2r[c],   d);
        d = fmaf(a.y, W2r[c+1], d);
        d = fmaf(a.z, W2r[c+2], d);
        d = fmaf(a.w, W2r[c+3], d);
      }
      float h2p = fmaf(kpp, d, b2r);
      float h2nv = fmaxf(0.f, fmaf(h2p, sc2r, sh2r));
      agg2u = fmaxf(agg2u, h2nv);
      h2n_lds[w][p2][lane] = h2nv;
    }
    // ---- Phase C: lane owns output channels {lane, lane+64} ----
    agg2_lds[w][lane] = agg2u;
    float t3a=0.f, t3b=0.f;
    #pragma unroll
    for (int c=0;c<64;++c){
      float a = agg2_lds[w][c];
      t3a = fmaf(a, sWd[(64+c)*128 + lane],      t3a);
      t3b = fmaf(a, sWd[(64+c)*128 + 64 + lane], t3b);
    }
    float acc0[NP], acc1[NP];
    #pragma unroll
    for (int p2=0;p2<NP;++p2){ acc0[p2]=0.f; acc1[p2]=0.f; }
    for (int cb=0; cb<64; cb+=4){
      float w00=sWd[(cb+0)*128+lane],    w01=sWd[(cb+1)*128+lane],
            w02=sWd[(cb+2)*128+lane],    w03=sWd[(cb+3)*128+lane];
      float w10=sWd[(cb+0)*128+64+lane], w11=sWd[(cb+1)*128+64+lane],
            w12=sWd[(cb+2)*128+64+lane], w13=sWd[(cb+3)*128+64+lane];
      #pragma unroll
      for (int p2=0;p2<NP;++p2){
        float4 a = *reinterpret_cast<const float4*>(&h2n_lds[w][p2][cb]);
        acc0[p2] = fmaf(a.x,w00, fmaf(a.y,w01, fmaf(a.z,w02, fmaf(a.w,w03, acc0[p2]))));
        acc1[p2] = fmaf(a.x,w10, fmaf(a.y,w11, fmaf(a.z,w12, fmaf(a.w,w13, acc1[p2]))));
      }
    }
    float mx0=-FLT_MAX, mx1=-FLT_MAX, mn0=FLT_MAX, mn1=FLT_MAX;
    #pragma unroll
    for (int p2=0;p2<NP;++p2){
      float kpp = h1n_lds[w][p2][16];
      float h0 = fmaf(kpp, acc0[p2]+t3a, bdr0);
      float h1 = fmaf(kpp, acc1[p2]+t3b, bdr1);
      s3a += h0; ss3a = fmaf(h0,h0,ss3a);
      s3b += h1; ss3b = fmaf(h1,h1,ss3b);
      mx0=fmaxf(mx0,h0); mn0=fminf(mn0,h0);
      mx1=fmaxf(mx1,h1); mn1=fminf(mn1,h1);
    }
    m3x[v*128+lane]    = mx0;  m3x[v*128+64+lane] = mx1;
    m3n[v*128+lane]    = mn0;  m3n[v*128+64+lane] = mn1;
  }
  atomicAdd(&ws[S3SUM+lane],    s3a);
  atomicAdd(&ws[S3SUM+64+lane], s3b);
  atomicAdd(&ws[S3SQ+lane],     ss3a);
  atomicAdd(&ws[S3SQ+64+lane],  ss3b);
}

__global__ __launch_bounds__(256) void k_scatter(const float* __restrict__ ws,
    const int* __restrict__ coord, const float* __restrict__ gd,
    const float* __restrict__ bed, float* __restrict__ out)
{
  __shared__ float s3c[128], s3h[128];
  int t = threadIdx.x;
  if (t < 128) {
    const float invN = 1.f/(float)NPTS;
    float mean = ws[S3SUM+t]*invN;
    float var  = ws[S3SQ+t]*invN - mean*mean;
    float sc = gd[t]*rsqrtf(var+1e-5f);
    s3c[t]=sc; s3h[t]=fmaf(-mean,sc,bed[t]);
  }
  __syncthreads();
  int tid = blockIdx.x*256 + t;
  if (tid >= NV*128) return;
  int v = tid >> 7, u = tid & 127;
  float sc = s3c[u], sh = s3h[u];
  // BN is monotone per channel: pick max or min of pre-BN h3 by sign of scale.
  float m = (sc >= 0.f) ? ws[M3MAX+tid] : ws[M3MIN+tid];
  float val = fmaxf(0.f, fmaf(m, sc, sh));
  if (val != 0.f) {
    int z = coord[v*3+0], y = coord[v*3+1], xx = coord[v*3+2];
    atomicAdd(&out[((u*10+z)*200+y)*176+xx], val);
  }
}

extern "C" void kernel_launch(void* const* d_in, const int* in_sizes, int n_in,
                              void* d_out, int out_size, void* d_ws, size_t ws_size,
                              hipStream_t stream)
{
  const float* x   = (const float*)d_in[0];
  const int*   coord = (const int*)d_in[1];
  const float* W1  = (const float*)d_in[2];
  const float* b1  = (const float*)d_in[3];
  const float* g1  = (const float*)d_in[4];
  const float* be1 = (const float*)d_in[5];
  const float* W2  = (const float*)d_in[6];
  const float* b2  = (const float*)d_in[7];
  const float* g2  = (const float*)d_in[8];
  const float* be2 = (const float*)d_in[9];
  const float* Wd  = (const float*)d_in[10];
  const float* bd  = (const float*)d_in[11];
  const float* gd  = (const float*)d_in[12];
  const float* bed = (const float*)d_in[13];
  float* out = (float*)d_out;
  float* ws  = (float*)d_ws;

  hipMemsetAsync(ws, 0, 1024*sizeof(float), stream);
  hipMemsetAsync(out, 0, (size_t)out_size*sizeof(float), stream);

  k_moments<<<640,256,0,stream>>>(x, ws);
  k_pass2<<<1024,256,0,stream>>>(x, W1,b1,g1,be1, W2,b2, ws);
  k_pass3<<<256,512,0,stream>>>(x, W1,b1,g1,be1, W2,b2,g2,be2, Wd,bd, ws);
  k_scatter<<<10000,256,0,stream>>>(ws, coord, gd, bed, out);
}